// Round 11
// baseline (456.338 us; speedup 1.0000x reference)
//
#include <hip/hip_runtime.h>
#include <hip/hip_fp16.h>
#include <cstdint>
#include <cstddef>

// Problem dims (fixed by the reference)
#define TT 1024
#define BB 64
#define DD 512
#define HH 1024
#define MM (TT * BB)   // 65536 rows for the batched GEMM

typedef _Float16 f16;
typedef _Float16 f16x8 __attribute__((ext_vector_type(8)));
typedef float f32x4 __attribute__((ext_vector_type(4)));

// ---------------------------------------------------------------- converts
__global__ void cvt_f32_to_f16(const float* __restrict__ src,
                               f16* __restrict__ dst, int n) {
    int i = blockIdx.x * blockDim.x + threadIdx.x;
    int idx = i * 8;
    if (idx + 8 <= n) {
        float4 a = *reinterpret_cast<const float4*>(src + idx);
        float4 b = *reinterpret_cast<const float4*>(src + idx + 4);
        f16x8 o;
        o[0] = (f16)a.x; o[1] = (f16)a.y; o[2] = (f16)a.z; o[3] = (f16)a.w;
        o[4] = (f16)b.x; o[5] = (f16)b.y; o[6] = (f16)b.z; o[7] = (f16)b.w;
        *reinterpret_cast<f16x8*>(dst + idx) = o;
    } else {
        for (int k = idx; k < n; ++k) dst[k] = (f16)src[k];
    }
}

// Both weight matrices in one launch (W0: n0 elems, then W1).
__global__ void cvt_weights(const float* __restrict__ W0, f16* __restrict__ W0h,
                            int n0, const float* __restrict__ W1,
                            f16* __restrict__ W1h) {
    int i = blockIdx.x * blockDim.x + threadIdx.x;
    int idx = i * 8;
    const float* s;
    f16* d;
    int off;
    if (idx < n0) { s = W0; d = W0h; off = idx; }
    else          { s = W1; d = W1h; off = idx - n0; }
    float4 a = *reinterpret_cast<const float4*>(s + off);
    float4 b = *reinterpret_cast<const float4*>(s + off + 4);
    f16x8 o;
    o[0] = (f16)a.x; o[1] = (f16)a.y; o[2] = (f16)a.z; o[3] = (f16)a.w;
    o[4] = (f16)b.x; o[5] = (f16)b.y; o[6] = (f16)b.z; o[7] = (f16)b.w;
    *reinterpret_cast<f16x8*>(d + off) = o;
}

// ---------------------------------------------------------------- common
__device__ __forceinline__ void gload16(const void* g, void* l) {
    __builtin_amdgcn_global_load_lds(
        (const __attribute__((address_space(1))) void*)g,
        (__attribute__((address_space(3))) void*)l, 16, 0, 0);
}

// Read an MFMA A/B fragment: tile-local row r, k-subtile s (0/1),
// k-group kg (0..3). Physical col 16B-chunk = (s*4 + kg) ^ (r&7).
// (row&7)<<4 XOR swizzle on 128-B rows: 0 bank conflicts (verified r5/r7).
__device__ __forceinline__ f16x8 ldfrag(const f16* buf, int r, int s,
                                        int kg) {
    int c = ((s * 4 + kg) ^ (r & 7)) << 4;
    return *reinterpret_cast<const f16x8*>((const char*)buf + r * 128 + c);
}

// ---------------------------------------------------------------- gemm5
// Champion simple structure (875 TF): 128x128 tile, BK=64, 4 waves,
// single-buffered 32 KiB LDS, 2-barrier K-loop, 3-4 blocks/CU overlap.
__device__ __forceinline__ void stage128x64(const f16* __restrict__ G,
                                            int rowbase, int K, int kt,
                                            f16* lbuf, int tid) {
    #pragma unroll
    for (int j = 0; j < 4; ++j) {
        int p   = (j * 256 + tid) * 16;        // physical byte in tile
        int row = p >> 7;                      // 0..127 (128-B rows)
        int lc  = (p & 127) ^ ((row & 7) << 4);// logical col byte
        gload16(G + (size_t)(rowbase + row) * K + kt * 64 + (lc >> 1),
                (char*)lbuf + p);
    }
}

template <typename TC>
__global__ __launch_bounds__(256, 4) void gemm5(
    const f16* __restrict__ A, const f16* __restrict__ W,
    const float* __restrict__ bias, TC* __restrict__ C,
    int M, int N, int K) {
    __shared__ f16 lds[2][128 * 64];   // A tile, B tile (32 KiB total)

    const int tid  = threadIdx.x;
    const int lane = tid & 63;
    const int wid  = tid >> 6;
    const int wm   = wid >> 1;
    const int wn   = wid & 1;
    const int lr   = lane & 15;
    const int kg   = lane >> 4;

    const int nwg = gridDim.x;
    int bid = blockIdx.x;
    int wg  = (nwg % 8 == 0) ? ((bid & 7) * (nwg >> 3) + (bid >> 3)) : bid;
    const int ncol = N >> 7;
    const int brow = (wg / ncol) << 7;
    const int bcol = (wg % ncol) << 7;

    const int NT = K >> 6;

    f32x4 acc[4][4] = {};

    for (int t = 0; t < NT; ++t) {
        __syncthreads();
        stage128x64(A, brow, K, t, lds[0], tid);
        stage128x64(W, bcol, K, t, lds[1], tid);
        __syncthreads();

        #pragma unroll
        for (int s = 0; s < 2; ++s) {
            f16x8 af[4], bf[4];
            #pragma unroll
            for (int m = 0; m < 4; ++m)
                af[m] = ldfrag(lds[0], wm * 64 + m * 16 + lr, s, kg);
            #pragma unroll
            for (int n = 0; n < 4; ++n)
                bf[n] = ldfrag(lds[1], wn * 64 + n * 16 + lr, s, kg);
            #pragma unroll
            for (int m = 0; m < 4; ++m)
                #pragma unroll
                for (int n = 0; n < 4; ++n)
                    acc[m][n] = __builtin_amdgcn_mfma_f32_16x16x32_f16(
                        af[m], bf[n], acc[m][n], 0, 0, 0);
        }
    }

    if constexpr (sizeof(TC) == 2) {
        f16* Ct = &lds[0][0];
        __syncthreads();
        #pragma unroll
        for (int fn = 0; fn < 4; ++fn) {
            int col = wn * 64 + fn * 16 + lr;
            float bv = bias[bcol + col];
            #pragma unroll
            for (int fm = 0; fm < 4; ++fm) {
                int row0 = wm * 64 + fm * 16 + kg * 4;
                #pragma unroll
                for (int j = 0; j < 4; ++j) {
                    int r  = row0 + j;
                    int pb = r * 256 + ((col * 2) ^ ((r & 7) << 4));
                    *(f16*)((char*)Ct + pb) = (f16)(acc[fm][fn][j] + bv);
                }
            }
        }
        __syncthreads();
        #pragma unroll
        for (int i = 0; i < 8; ++i) {
            int e   = (i * 256 + tid) * 16;
            int row = e >> 8;
            int cb  = e & 255;
            int pb  = row * 256 + (cb ^ ((row & 7) << 4));
            f16x8 v = *(const f16x8*)((const char*)Ct + pb);
            *reinterpret_cast<f16x8*>(
                (f16*)C + (size_t)(brow + row) * N + bcol + (cb >> 1)) = v;
        }
    } else {
        #pragma unroll
        for (int fn = 0; fn < 4; ++fn) {
            int col = bcol + wn * 64 + fn * 16 + lr;
            float bv = bias[col];
            #pragma unroll
            for (int fm = 0; fm < 4; ++fm) {
                int row0 = brow + wm * 64 + fm * 16 + kg * 4;
                #pragma unroll
                for (int j = 0; j < 4; ++j)
                    C[(size_t)(row0 + j) * N + col] = (TC)(acc[fm][fn][j] + bv);
            }
        }
    }
}

// ---------------------------------------------------------------- gemm8
// Counted-vmcnt phase schedule, RING-OF-3 (race-free): BM=128, BN=256,
// BK=64, 8 waves (2M x 4N, 64x64 out each), 144 KiB LDS (3 x [A 16K|B 32K]).
// Per K-step: 2 phases x {ds_read subtile; stage 1 half; barrier; lgkm(0);
// setprio+16 MFMA; barrier}; vmcnt(6) once per K-step (tile t+2 in flight,
// forces t+1 landed). sched_barrier(0) pins phase boundaries.
__device__ __forceinline__ void stageA8(const f16* __restrict__ G,
                                        int rowbase, int K, int kt,
                                        f16* lbuf, int tid) {
    #pragma unroll
    for (int j = 0; j < 2; ++j) {          // 128x64 f16 = 16 KB
        int p   = (j * 512 + tid) * 16;
        int row = p >> 7;                  // 0..127
        int lc  = (p & 127) ^ ((row & 7) << 4);
        gload16(G + (size_t)(rowbase + row) * K + kt * 64 + (lc >> 1),
                (char*)lbuf + p);
    }
}
__device__ __forceinline__ void stageB8(const f16* __restrict__ G,
                                        int rowbase, int K, int kt,
                                        f16* lbuf, int tid) {
    #pragma unroll
    for (int j = 0; j < 4; ++j) {          // 256x64 f16 = 32 KB
        int p   = (j * 512 + tid) * 16;
        int row = p >> 7;                  // 0..255
        int lc  = (p & 127) ^ ((row & 7) << 4);
        gload16(G + (size_t)(rowbase + row) * K + kt * 64 + (lc >> 1),
                (char*)lbuf + p);
    }
}

__global__ __launch_bounds__(512, 1) void gemm8(
    const f16* __restrict__ A, const f16* __restrict__ W,
    const float* __restrict__ bias, f16* __restrict__ C,
    int M, int N, int K) {
    __shared__ __align__(16) char smem[3 * 49152];   // 144 KiB ring

    const int tid  = threadIdx.x;
    const int lane = tid & 63;
    const int wid  = tid >> 6;      // 0..7
    const int wm   = wid >> 2;      // 0..1 -> 64-row strip of 128
    const int wn   = wid & 3;       // 0..3 -> 64-col strip of 256
    const int lr   = lane & 15;
    const int kg   = lane >> 4;

    // XCD-bijective swizzle, col-fastest (nwg % 8 == 0 here)
    const int nwg = gridDim.x;
    int bid = blockIdx.x;
    int wg  = (nwg % 8 == 0) ? ((bid & 7) * (nwg >> 3) + (bid >> 3)) : bid;
    const int ncol = N >> 8;                // N/256
    const int brow = (wg / ncol) << 7;      // *128
    const int bcol = (wg % ncol) << 8;      // *256

    const int NT = K >> 6;

    f32x4 acc[4][4] = {};

    // Prologue: stage tiles 0,1 (12 loads); vmcnt(6) -> tile 0 landed.
    stageA8(A, brow, K, 0, (f16*)(smem +      0), tid);
    stageB8(W, bcol, K, 0, (f16*)(smem +  16384), tid);
    stageA8(A, brow, K, 1, (f16*)(smem +  49152), tid);
    stageB8(W, bcol, K, 1, (f16*)(smem +  65536), tid);
    asm volatile("s_waitcnt vmcnt(6)" ::: "memory");
    __builtin_amdgcn_s_barrier();

    for (int t = 0; t < NT; ++t) {
        const int cs = t % 3;
        const f16* As = (const f16*)(smem + cs * 49152);
        const f16* Bs = (const f16*)(smem + cs * 49152 + 16384);
        const int u  = t + 2;
        const bool st = (u < NT);
        const int us = u % 3;

        f16x8 aA[4][2], bB[4][2];
        // ---- phase 0: read A m0..3 (8) + B n0,n1 (4); stage A(t+2)
        #pragma unroll
        for (int m = 0; m < 4; ++m)
            #pragma unroll
            for (int s = 0; s < 2; ++s)
                aA[m][s] = ldfrag(As, wm * 64 + m * 16 + lr, s, kg);
        #pragma unroll
        for (int n = 0; n < 2; ++n)
            #pragma unroll
            for (int s = 0; s < 2; ++s)
                bB[n][s] = ldfrag(Bs, wn * 64 + n * 16 + lr, s, kg);
        if (st) stageA8(A, brow, K, u, (f16*)(smem + us * 49152), tid);
        __builtin_amdgcn_s_barrier();
        asm volatile("s_waitcnt lgkmcnt(0)" ::: "memory");
        __builtin_amdgcn_sched_barrier(0);
        __builtin_amdgcn_s_setprio(1);
        #pragma unroll
        for (int s = 0; s < 2; ++s)
            #pragma unroll
            for (int m = 0; m < 4; ++m)
                #pragma unroll
                for (int n = 0; n < 2; ++n)
                    acc[m][n] = __builtin_amdgcn_mfma_f32_16x16x32_f16(
                        aA[m][s], bB[n][s], acc[m][n], 0, 0, 0);
        __builtin_amdgcn_s_setprio(0);
        __builtin_amdgcn_sched_barrier(0);
        __builtin_amdgcn_s_barrier();

        // ---- phase 1: read B n2,n3 (4); stage B(t+2); gate vmcnt(6)
        #pragma unroll
        for (int n = 0; n < 2; ++n)
            #pragma unroll
            for (int s = 0; s < 2; ++s)
                bB[2 + n][s] = ldfrag(Bs, wn * 64 + (2 + n) * 16 + lr, s, kg);
        if (st) stageB8(W, bcol, K, u, (f16*)(smem + us * 49152 + 16384), tid);
        __builtin_amdgcn_s_barrier();
        asm volatile("s_waitcnt lgkmcnt(0)" ::: "memory");
        __builtin_amdgcn_sched_barrier(0);
        __builtin_amdgcn_s_setprio(1);
        #pragma unroll
        for (int s = 0; s < 2; ++s)
            #pragma unroll
            for (int m = 0; m < 4; ++m)
                #pragma unroll
                for (int n = 0; n < 2; ++n)
                    acc[m][2 + n] = __builtin_amdgcn_mfma_f32_16x16x32_f16(
                        aA[m][s], bB[2 + n][s], acc[m][2 + n], 0, 0, 0);
        __builtin_amdgcn_s_setprio(0);
        __builtin_amdgcn_sched_barrier(0);
        if (st)              { asm volatile("s_waitcnt vmcnt(6)" ::: "memory"); }
        else if (t + 1 < NT) { asm volatile("s_waitcnt vmcnt(0)" ::: "memory"); }
        __builtin_amdgcn_s_barrier();
    }

    // Epilogue: LDS repack [128][256] f16 (512-B rows, (r&7)<<4 swizzle),
    // then coalesced 16-B stores.  C/D frag: col=lane&15, row=(lane>>4)*4+j.
    f16* Ct = (f16*)smem;
    __syncthreads();
    #pragma unroll
    for (int fn = 0; fn < 4; ++fn) {
        int col = wn * 64 + fn * 16 + lr;
        float bv = bias[bcol + col];
        #pragma unroll
        for (int fm = 0; fm < 4; ++fm) {
            int row0 = wm * 64 + fm * 16 + kg * 4;
            #pragma unroll
            for (int j = 0; j < 4; ++j) {
                int r  = row0 + j;
                int pb = r * 512 + ((col * 2) ^ ((r & 7) << 4));
                *(f16*)((char*)Ct + pb) = (f16)(acc[fm][fn][j] + bv);
            }
        }
    }
    __syncthreads();
    #pragma unroll
    for (int i = 0; i < 8; ++i) {
        int e   = (i * 512 + tid) * 16;     // byte in [128][512B]
        int row = e >> 9;
        int cb  = e & 511;
        int pb  = row * 512 + (cb ^ ((row & 7) << 4));
        f16x8 v = *(const f16x8*)((const char*)Ct + pb);
        *reinterpret_cast<f16x8*>(
            C + (size_t)(brow + row) * N + bcol + (cb >> 1)) = v;
    }
}

// ---------------------------------------------------------------- scan
__device__ __forceinline__ float fast_tanh(float x) {
    float e = __builtin_amdgcn_exp2f(x * 2.8853900817779268f);  // exp(2x)
    float r = __builtin_amdgcn_rcpf(e + 1.0f);
    return 1.0f - 2.0f * r;
}

template <typename TI, typename TO, int PF, bool ZTAIL>
__global__ __launch_bounds__(256) void scan_kernel(
    const TI* __restrict__ pre, const float* __restrict__ w,
    TO* __restrict__ out) {
    const int S = BB * HH;  // 65536
    const int idx = blockIdx.x * blockDim.x + threadIdx.x;
    const float wv = w[idx & (HH - 1)];
    const TI* p = pre + idx;
    TO* o = out + idx;

    float buf[PF];
    #pragma unroll
    for (int i = 0; i < PF; ++i) buf[i] = (float)p[(size_t)i * S];

    float h = 0.f;
    for (int t0 = 0; t0 < TT; t0 += PF) {
        float nbuf[PF];
        #pragma unroll
        for (int i = 0; i < PF; ++i) {
            int tp = t0 + PF + i;
            tp = (tp < TT - 1) ? tp : (TT - 1);
            nbuf[i] = (float)p[(size_t)tp * S];
        }
        #pragma unroll
        for (int i = 0; i < PF; ++i) {
            h = fast_tanh(fmaf(h, wv, buf[i]));
            o[(size_t)(t0 + i) * S] = (TO)h;
        }
        #pragma unroll
        for (int i = 0; i < PF; ++i) buf[i] = nbuf[i];
    }
    if constexpr (ZTAIL) {
        o[(size_t)TT * S] = (TO)0.f;
        o[(size_t)(TT + 1) * S] = (TO)0.f;
    }
}

// ---------------------------------------------------------------- launch
extern "C" void kernel_launch(void* const* d_in, const int* in_sizes, int n_in,
                              void* d_out, int out_size, void* d_ws, size_t ws_size,
                              hipStream_t stream) {
    const float* x  = (const float*)d_in[0];  // [T,B,D]
    const float* W0 = (const float*)d_in[1];  // [H,D]
    const float* w0 = (const float*)d_in[2];  // [H]
    const float* b0 = (const float*)d_in[3];  // [H]
    const float* W1 = (const float*)d_in[4];  // [H,H]
    const float* w1 = (const float*)d_in[5];  // [H]
    const float* b1 = (const float*)d_in[6];  // [H]
    float* out = (float*)d_out;

    const size_t SZ_big = (size_t)MM * HH * sizeof(f16);      // 134 MB
    const size_t O_W0   = SZ_big;
    const size_t O_W1   = O_W0 + (size_t)HH * DD * sizeof(f16);
    const size_t O_pre1 = O_W1 + (size_t)HH * HH * sizeof(f16);
    const bool f16pre1  = (ws_size >= O_pre1 + SZ_big);

    f16* big   = (f16*)d_ws;
    f16* W0h   = (f16*)((char*)d_ws + O_W0);
    f16* W1h   = (f16*)((char*)d_ws + O_W1);
    f16* pre1h = (f16*)((char*)d_ws + O_pre1);

    const int nwg5 = (MM / 128) * (HH / 128);   // 4096 blocks (gemm5)
    const int nwg8 = (MM / 128) * (HH / 256);   // 2048 blocks (gemm8)

    // 1) converts: x (big pass) + both weights (one small launch)
    cvt_f32_to_f16<<<(MM * DD) / 8 / 256, 256, 0, stream>>>(x, big, MM * DD);
    cvt_weights<<<(HH * DD + HH * HH) / 8 / 256, 256, 0, stream>>>(
        W0, W0h, HH * DD, W1, W1h);

    // 2) pre0 = x_f16 @ W0^T + b0 -> d_out (champion gemm5 structure)
    gemm5<f16><<<nwg5, 256, 0, stream>>>(big, W0h, b0, (f16*)d_out, MM, HH, DD);

    // 3) scan layer 0: pre0(f16, d_out) -> out0(f16) into ws big region
    scan_kernel<f16, f16, 32, false><<<(BB * HH) / 256, 256, 0, stream>>>(
        (const f16*)d_out, w0, big);

    if (f16pre1) {
        // 4) pre1 = out0 @ W1^T + b1 (f16) -> ws  (ring-3 counted-vmcnt gemm8)
        gemm8<<<nwg8, 512, 0, stream>>>(big, W1h, b1, pre1h, MM, HH, HH);
        // 5) scan layer 1: pre1(f16, ws) -> out (f32); zeros hidden tail
        scan_kernel<f16, float, 32, true><<<(BB * HH) / 256, 256, 0, stream>>>(
            pre1h, w1, out);
    } else {
        // 4) pre1 (f32) -> d_out, then in-place scan
        gemm5<float><<<nwg5, 256, 0, stream>>>(big, W1h, b1, out, MM, HH, HH);
        scan_kernel<float, float, 32, true><<<(BB * HH) / 256, 256, 0, stream>>>(
            out, w1, out);
    }
}

// Round 12
// 424.795 us; speedup vs baseline: 1.0743x; 1.0743x over previous
//
#include <hip/hip_runtime.h>
#include <hip/hip_fp16.h>
#include <cstdint>
#include <cstddef>

// Problem dims (fixed by the reference)
#define TT 1024
#define BB 64
#define DD 512
#define HH 1024
#define MM (TT * BB)   // 65536 rows for the batched GEMM

typedef _Float16 f16;
typedef _Float16 f16x8 __attribute__((ext_vector_type(8)));
typedef float f32x4 __attribute__((ext_vector_type(4)));

// ---------------------------------------------------------------- converts
__global__ void cvt_f32_to_f16(const float* __restrict__ src,
                               f16* __restrict__ dst, int n) {
    int i = blockIdx.x * blockDim.x + threadIdx.x;
    int idx = i * 8;
    if (idx + 8 <= n) {
        float4 a = *reinterpret_cast<const float4*>(src + idx);
        float4 b = *reinterpret_cast<const float4*>(src + idx + 4);
        f16x8 o;
        o[0] = (f16)a.x; o[1] = (f16)a.y; o[2] = (f16)a.z; o[3] = (f16)a.w;
        o[4] = (f16)b.x; o[5] = (f16)b.y; o[6] = (f16)b.z; o[7] = (f16)b.w;
        *reinterpret_cast<f16x8*>(dst + idx) = o;
    } else {
        for (int k = idx; k < n; ++k) dst[k] = (f16)src[k];
    }
}

// Both weight matrices in one launch (W0: n0 elems, then W1).
__global__ void cvt_weights(const float* __restrict__ W0, f16* __restrict__ W0h,
                            int n0, const float* __restrict__ W1,
                            f16* __restrict__ W1h) {
    int i = blockIdx.x * blockDim.x + threadIdx.x;
    int idx = i * 8;
    const float* s;
    f16* d;
    int off;
    if (idx < n0) { s = W0; d = W0h; off = idx; }
    else          { s = W1; d = W1h; off = idx - n0; }
    float4 a = *reinterpret_cast<const float4*>(s + off);
    float4 b = *reinterpret_cast<const float4*>(s + off + 4);
    f16x8 o;
    o[0] = (f16)a.x; o[1] = (f16)a.y; o[2] = (f16)a.z; o[3] = (f16)a.w;
    o[4] = (f16)b.x; o[5] = (f16)b.y; o[6] = (f16)b.z; o[7] = (f16)b.w;
    *reinterpret_cast<f16x8*>(d + off) = o;
}

// ---------------------------------------------------------------- GEMM
// C[M,N] = A[M,K] (f16 row-major) * W[N,K]^T (f16 row-major) + bias[N]
// 128x128 tile, BK=64, 4 waves (2x2 of 64x64), SINGLE-buffered 32 KiB LDS,
// simple 2-barrier K-loop; overlap from 3-4 independent blocks/CU
// (m97 mechanism; measured: 875 TF, MfmaUtil 39.5%, 0 bank conflicts —
// at the plain-HIP 2-barrier-structure ceiling; four deep-pipeline
// attempts r2/r5/r6/r11 all measured below this).
// (row&7)<<4 XOR swizzle on 128-B LDS rows.
__device__ __forceinline__ void gload16(const void* g, void* l) {
    __builtin_amdgcn_global_load_lds(
        (const __attribute__((address_space(1))) void*)g,
        (__attribute__((address_space(3))) void*)l, 16, 0, 0);
}

// Stage one 128x64 f16 K-tile (16 KiB): 256 threads x 4 x 16B.
// LDS dest lane-linear (gload_lds requirement); swizzle applied by
// inverse-permuting the GLOBAL source address (m173 pattern).
__device__ __forceinline__ void stage128x64(const f16* __restrict__ G,
                                            int rowbase, int K, int kt,
                                            f16* lbuf, int tid) {
    #pragma unroll
    for (int j = 0; j < 4; ++j) {
        int p   = (j * 256 + tid) * 16;        // physical byte in tile
        int row = p >> 7;                      // 0..127 (128-B rows)
        int lc  = (p & 127) ^ ((row & 7) << 4);// logical col byte
        gload16(G + (size_t)(rowbase + row) * K + kt * 64 + (lc >> 1),
                (char*)lbuf + p);
    }
}

// Read an MFMA A/B fragment: tile-local row r, k-subtile s (0/1),
// k-group kg (0..3). Physical col 16B-chunk = (s*4 + kg) ^ (r&7).
__device__ __forceinline__ f16x8 ldfrag(const f16* buf, int r, int s,
                                        int kg) {
    int c = ((s * 4 + kg) ^ (r & 7)) << 4;
    return *reinterpret_cast<const f16x8*>((const char*)buf + r * 128 + c);
}

template <typename TC>
__global__ __launch_bounds__(256, 4) void gemm5(
    const f16* __restrict__ A, const f16* __restrict__ W,
    const float* __restrict__ bias, TC* __restrict__ C,
    int M, int N, int K) {
    __shared__ f16 lds[2][128 * 64];   // A tile, B tile (32 KiB total)

    const int tid  = threadIdx.x;
    const int lane = tid & 63;
    const int wid  = tid >> 6;      // 0..3
    const int wm   = wid >> 1;      // 0..1 -> 64-row strip
    const int wn   = wid & 1;       // 0..1 -> 64-col strip
    const int lr   = lane & 15;
    const int kg   = lane >> 4;     // 0..3

    // XCD-bijective block swizzle (nwg % 8 == 0 here), col-fastest chunks
    const int nwg = gridDim.x;
    int bid = blockIdx.x;
    int wg  = (nwg % 8 == 0) ? ((bid & 7) * (nwg >> 3) + (bid >> 3)) : bid;
    const int ncol = N >> 7;                 // N/128 col-blocks
    const int brow = (wg / ncol) << 7;
    const int bcol = (wg % ncol) << 7;

    const int NT = K >> 6;          // K-tiles of 64

    f32x4 acc[4][4] = {};

    for (int t = 0; t < NT; ++t) {
        __syncthreads();   // all waves done reading the previous tile
        stage128x64(A, brow, K, t, lds[0], tid);
        stage128x64(W, bcol, K, t, lds[1], tid);
        __syncthreads();   // compiler drains vmcnt(0) before barrier

        #pragma unroll
        for (int s = 0; s < 2; ++s) {
            f16x8 af[4], bf[4];
            #pragma unroll
            for (int m = 0; m < 4; ++m)
                af[m] = ldfrag(lds[0], wm * 64 + m * 16 + lr, s, kg);
            #pragma unroll
            for (int n = 0; n < 4; ++n)
                bf[n] = ldfrag(lds[1], wn * 64 + n * 16 + lr, s, kg);
            #pragma unroll
            for (int m = 0; m < 4; ++m)
                #pragma unroll
                for (int n = 0; n < 4; ++n)
                    acc[m][n] = __builtin_amdgcn_mfma_f32_16x16x32_f16(
                        af[m], bf[n], acc[m][n], 0, 0, 0);
        }
    }

    // Epilogue. C/D frag layout: col = lane&15, row = (lane>>4)*4 + j.
    if constexpr (sizeof(TC) == 2) {
        // LDS repack: 32 KiB = [128][128] f16 C-tile, 256-B rows,
        // (row&7)<<4 XOR swizzle; then coalesced 16-B global stores.
        f16* Ct = &lds[0][0];
        __syncthreads();   // all waves done with LDS tiles
        #pragma unroll
        for (int fn = 0; fn < 4; ++fn) {
            int col = wn * 64 + fn * 16 + lr;
            float bv = bias[bcol + col];
            #pragma unroll
            for (int fm = 0; fm < 4; ++fm) {
                int row0 = wm * 64 + fm * 16 + kg * 4;
                #pragma unroll
                for (int j = 0; j < 4; ++j) {
                    int r  = row0 + j;
                    int pb = r * 256 + ((col * 2) ^ ((r & 7) << 4));
                    *(f16*)((char*)Ct + pb) = (f16)(acc[fm][fn][j] + bv);
                }
            }
        }
        __syncthreads();
        #pragma unroll
        for (int i = 0; i < 8; ++i) {
            int e   = (i * 256 + tid) * 16;     // byte in [128][256B]
            int row = e >> 8;
            int cb  = e & 255;
            int pb  = row * 256 + (cb ^ ((row & 7) << 4));
            f16x8 v = *(const f16x8*)((const char*)Ct + pb);
            *reinterpret_cast<f16x8*>(
                (f16*)C + (size_t)(brow + row) * N + bcol + (cb >> 1)) = v;
        }
    } else {
        // f32 fallback (unused when ws fits f16 pre1): scattered stores
        #pragma unroll
        for (int fn = 0; fn < 4; ++fn) {
            int col = bcol + wn * 64 + fn * 16 + lr;
            float bv = bias[col];
            #pragma unroll
            for (int fm = 0; fm < 4; ++fm) {
                int row0 = brow + wm * 64 + fm * 16 + kg * 4;
                #pragma unroll
                for (int j = 0; j < 4; ++j)
                    C[(size_t)(row0 + j) * N + col] = (TC)(acc[fm][fn][j] + bv);
            }
        }
    }
}

// ---------------------------------------------------------------- scan
// h_t = tanh(pre_t + h_{t-1} * w), one thread per (b,h) element.
// PF-deep branchless load pipeline; tiny body so clang fully unrolls and
// buf[] stays in VGPRs (rule #20).  ZTAIL: also zero the [2,B,H] hidden
// output right after the [T,B,H] block (saves a launch).
__device__ __forceinline__ float fast_tanh(float x) {
    float e = __builtin_amdgcn_exp2f(x * 2.8853900817779268f);  // exp(2x)
    float r = __builtin_amdgcn_rcpf(e + 1.0f);
    return 1.0f - 2.0f * r;
}

template <typename TI, typename TO, int PF, bool ZTAIL>
__global__ __launch_bounds__(256) void scan_kernel(
    const TI* __restrict__ pre, const float* __restrict__ w,
    TO* __restrict__ out) {
    const int S = BB * HH;  // 65536
    const int idx = blockIdx.x * blockDim.x + threadIdx.x;
    const float wv = w[idx & (HH - 1)];
    const TI* p = pre + idx;
    TO* o = out + idx;

    float buf[PF];
    #pragma unroll
    for (int i = 0; i < PF; ++i) buf[i] = (float)p[(size_t)i * S];

    float h = 0.f;
    for (int t0 = 0; t0 < TT; t0 += PF) {
        float nbuf[PF];
        #pragma unroll
        for (int i = 0; i < PF; ++i) {
            int tp = t0 + PF + i;
            tp = (tp < TT - 1) ? tp : (TT - 1);
            nbuf[i] = (float)p[(size_t)tp * S];
        }
        #pragma unroll
        for (int i = 0; i < PF; ++i) {
            h = fast_tanh(fmaf(h, wv, buf[i]));
            o[(size_t)(t0 + i) * S] = (TO)h;
        }
        #pragma unroll
        for (int i = 0; i < PF; ++i) buf[i] = nbuf[i];
    }
    if constexpr (ZTAIL) {
        o[(size_t)TT * S] = (TO)0.f;
        o[(size_t)(TT + 1) * S] = (TO)0.f;
    }
}

// ---------------------------------------------------------------- launch
extern "C" void kernel_launch(void* const* d_in, const int* in_sizes, int n_in,
                              void* d_out, int out_size, void* d_ws, size_t ws_size,
                              hipStream_t stream) {
    const float* x  = (const float*)d_in[0];  // [T,B,D]
    const float* W0 = (const float*)d_in[1];  // [H,D]
    const float* w0 = (const float*)d_in[2];  // [H]
    const float* b0 = (const float*)d_in[3];  // [H]
    const float* W1 = (const float*)d_in[4];  // [H,H]
    const float* w1 = (const float*)d_in[5];  // [H]
    const float* b1 = (const float*)d_in[6];  // [H]
    float* out = (float*)d_out;

    // ws layout: big f16 region (x_f16, then out0_f16) | W0 f16 | W1 f16 |
    //            pre1 f16 (if it fits)
    const size_t SZ_big = (size_t)MM * HH * sizeof(f16);      // 134 MB
    const size_t O_W0   = SZ_big;
    const size_t O_W1   = O_W0 + (size_t)HH * DD * sizeof(f16);
    const size_t O_pre1 = O_W1 + (size_t)HH * HH * sizeof(f16);
    const bool f16pre1  = (ws_size >= O_pre1 + SZ_big);

    f16* big   = (f16*)d_ws;
    f16* W0h   = (f16*)((char*)d_ws + O_W0);
    f16* W1h   = (f16*)((char*)d_ws + O_W1);
    f16* pre1h = (f16*)((char*)d_ws + O_pre1);

    const int nwg = (MM / 128) * (HH / 128);   // 4096 blocks

    // 1) converts: x (big pass) + both weights (one small launch)
    cvt_f32_to_f16<<<(MM * DD) / 8 / 256, 256, 0, stream>>>(x, big, MM * DD);
    cvt_weights<<<(HH * DD + HH * HH) / 8 / 256, 256, 0, stream>>>(
        W0, W0h, HH * DD, W1, W1h);

    // 2) pre0 = x_f16 @ W0^T + b0 -> d_out reused as f16 scratch
    gemm5<f16><<<nwg, 256, 0, stream>>>(big, W0h, b0, (f16*)d_out, MM, HH, DD);

    // 3) scan layer 0: pre0(f16, d_out) -> out0(f16) into ws big region
    scan_kernel<f16, f16, 32, false><<<(BB * HH) / 256, 256, 0, stream>>>(
        (const f16*)d_out, w0, big);

    if (f16pre1) {
        // 4) pre1 = out0 @ W1^T + b1 (f16) -> ws
        gemm5<f16><<<nwg, 256, 0, stream>>>(big, W1h, b1, pre1h, MM, HH, HH);
        // 5) scan layer 1: pre1(f16, ws) -> out (f32); zeros hidden tail
        scan_kernel<f16, float, 32, true><<<(BB * HH) / 256, 256, 0, stream>>>(
            pre1h, w1, out);
    } else {
        // 4) pre1 (f32) -> d_out, then in-place scan
        gemm5<float><<<nwg, 256, 0, stream>>>(big, W1h, b1, out, MM, HH, HH);
        scan_kernel<float, float, 32, true><<<(BB * HH) / 256, 256, 0, stream>>>(
            out, w1, out);
    }
}